// Round 6
// baseline (2915.122 us; speedup 1.0000x reference)
//
#include <hip/hip_runtime.h>

// HMM scaled-forward — A/B round.
// V1 (seqs 0..63):  all 32 A-chunks in regs + amdgpu_waves_per_eu(4,4)
//                   (tests whether the max-waves bound unlocks the 512-reg
//                    budget; rounds 3-5 spilled at >=128 A-words).
// V2 (seqs 64..127): proven round-2 A-split (24 reg + 8 LDS chunks) with the
//                    fused 512-wide phase2 + parity red2 (no serial epilogue).
// Both: 64 wgs x 1024 threads = 8 q-groups x 128 col-threads, one wg per
// (m,b) sequence; u kept unnormalized, 1/S folded into next step.

typedef _Float16 h2 __attribute__((ext_vector_type(2)));
typedef _Float16 h8 __attribute__((ext_vector_type(8)));

constexpr int Q = 512;
constexpr int L = 512;
constexpr int M = 2;
constexpr int B = 64;
constexpr int NTH = 1024;     // 8 q-groups x 128 col-threads
constexpr int CHUNKS = 32;    // h8 chunks per thread (128 h2 words)
constexpr float EPS = 1e-16f;

__device__ __forceinline__ float fdot2(h2 a, h2 b, float c) {
#if __has_builtin(__builtin_amdgcn_fdot2)
    return __builtin_amdgcn_fdot2(a, b, c, false);
#else
    return fmaf((float)a.x, (float)b.x, fmaf((float)a.y, (float)b.y, c));
#endif
}

// pack A (M,Q,Q) f32 -> per-thread chunk layout, f16 pairs over q.
// chunk c of thread t (qg=t>>7, ct=t&127): word j = (A[m][qg*64+2c][4ct+j],
// A[m][qg*64+2c+1][4ct+j]), stored at wsA[(m*32+c)*1024 + t].
__global__ __launch_bounds__(256) void pack_A(const float* __restrict__ A,
                                              uint4* __restrict__ wsA) {
    int idx = blockIdx.x * 256 + threadIdx.x;
    int t = idx & (NTH - 1);
    int c = (idx >> 10) & (CHUNKS - 1);
    int m = idx >> 15;
    int qg = t >> 7, ct = t & 127;
    int q0 = qg * 64 + 2 * c;
    const float* a0 = A + ((size_t)m * Q + q0) * Q + 4 * ct;
    float4 r0 = *(const float4*)a0;
    float4 r1 = *(const float4*)(a0 + Q);
    union { h2 w[4]; uint4 v; } cv;
    cv.w[0].x = (_Float16)r0.x; cv.w[0].y = (_Float16)r1.x;
    cv.w[1].x = (_Float16)r0.y; cv.w[1].y = (_Float16)r1.y;
    cv.w[2].x = (_Float16)r0.z; cv.w[2].y = (_Float16)r1.z;
    cv.w[3].x = (_Float16)r0.w; cv.w[3].y = (_Float16)r1.w;
    wsA[idx] = cv.v;
}

// Shared-memory layout helper (dynamic smem):
//   [0, LCH*NTH*16)            ldsA   (A chunks kept in LDS; absent if LCH=0)
//   [+0, +1024)                ldsU   (256 h2 words: u as f16 pairs)
//   [+1024, +1024+16384)       red    (8 x 512 f32 partials)
//   [+.., +64)                 red2   (2 x 8 f32, parity double-buffered)
template<int VCH>
__device__ __forceinline__ void hmm_body(const float* __restrict__ emis,
                                         const uint4* __restrict__ wsA,
                                         const float* __restrict__ initd,
                                         float* __restrict__ out, int bid) {
    constexpr int LCH = CHUNKS - VCH;
    extern __shared__ char smem[];
    uint4* ldsA = (uint4*)smem;
    h2*    ldsU = (h2*)(smem + (size_t)LCH * NTH * 16);
    float* red  = (float*)(smem + (size_t)LCH * NTH * 16 + 1024);
    float (*red2)[8] = (float (*)[8])(smem + (size_t)LCH * NTH * 16 + 1024 + 16384);

    const int t   = threadIdx.x;
    const int m   = bid >> 6;
    const int qg  = t >> 7;

    // ---- one-time A staging ----
    const uint4* wa = wsA + (size_t)m * CHUNKS * NTH + t;
    h8 areg[VCH];
    #pragma unroll
    for (int c = 0; c < VCH; ++c)
        areg[c] = *(const h8*)(wa + (size_t)c * NTH);
    if constexpr (LCH > 0) {
        #pragma unroll
        for (int s = 0; s < LCH; ++s)
            ldsA[s * NTH + t] = wa[(size_t)(VCH + s) * NTH];
    }

    const float* E = emis + (size_t)bid * Q;       // (t=0, m, b, :)
    const size_t stepStride = (size_t)M * B * Q;

    float ll = 0.0f;

    // ---- init: u0 = max(E0,eps) * max(init,eps), one state per thread ----
    if (t < Q) {
        float u = fmaxf(E[t], EPS) * fmaxf(initd[m * Q + t], EPS);
        float uy = __shfl_xor(u, 1, 64);
        if (!(t & 1)) { h2 w; w.x = (_Float16)u; w.y = (_Float16)uy; ldsU[t >> 1] = w; }
        float s = u;
        #pragma unroll
        for (int off = 32; off >= 1; off >>= 1) s += __shfl_xor(s, off, 64);
        if ((t & 63) == 0) red2[0][t >> 6] = s;
    }
    __syncthreads();   // covers ldsA/ldsU/red2 staging

    const float* Ep = E + stepStride + t;   // E[step][...][t], step=1

    for (int step = 1; step < L; ++step) {
        const int pp = (step + 1) & 1;      // red2 buffer holding S(step-1)
        const int cp = step & 1;

        float ep = 0.0f;
        if (t < Q) ep = *Ep;                // prefetch, consumed in phase2
        Ep += stepStride;

        // ---- phase1: 4 output cols x 64 q of my q-group ----
        float a0 = 0.f, a1 = 0.f, a2 = 0.f, a3 = 0.f;
        const h8* uq8 = (const h8*)(ldsU + qg * 32);   // wave-uniform broadcast
        #pragma unroll
        for (int i = 0; i < 8; ++i) {
            h8 uw = uq8[i];
            h2 ups[4] = {uw.lo.lo, uw.lo.hi, uw.hi.lo, uw.hi.hi};
            #pragma unroll
            for (int p = 0; p < 4; ++p) {
                const int c = 4 * i + p;
                h8 aw;
                if constexpr (LCH > 0) {
                    aw = (c < VCH) ? areg[c]
                                   : *(const h8*)(ldsA + (c - VCH) * NTH + t);
                } else {
                    aw = areg[c];
                }
                a0 = fdot2(aw.lo.lo, ups[p], a0);
                a1 = fdot2(aw.lo.hi, ups[p], a1);
                a2 = fdot2(aw.hi.lo, ups[p], a2);
                a3 = fdot2(aw.hi.hi, ups[p], a3);
            }
        }
        float4 rv; rv.x = a0; rv.y = a1; rv.z = a2; rv.w = a3;
        *(float4*)(&red[qg * Q + 4 * (t & 127)]) = rv;
        __syncthreads();

        // ---- phase2 (t<512): S(prev) from red2, 8-way reduce, renorm ----
        if (t < Q) {
            float4 rA = *(const float4*)&red2[pp][0];
            float4 rB = *(const float4*)&red2[pp][4];
            float acc = 0.f;
            #pragma unroll
            for (int g = 0; g < 8; ++g) acc += red[g * Q + t];
            float Sv = ((rA.x + rA.y) + (rA.z + rA.w)) +
                       ((rB.x + rB.y) + (rB.z + rB.w));
            float inv = 1.0f / Sv;
            ll += __logf(Sv);
            float r = fmaxf(acc * inv, EPS);
            float e = fmaxf(ep, EPS);
            float u = e * r;
            float uy = __shfl_xor(u, 1, 64);
            if (!(t & 1)) { h2 w; w.x = (_Float16)u; w.y = (_Float16)uy; ldsU[t >> 1] = w; }
            float s = u;
            #pragma unroll
            for (int off = 32; off >= 1; off >>= 1) s += __shfl_xor(s, off, 64);
            if ((t & 63) == 0) red2[cp][t >> 6] = s;
        }
        __syncthreads();
    }

    if (t == 0) {
        const float* r2 = red2[(L - 1) & 1];
        float Sv = ((r2[0] + r2[1]) + (r2[2] + r2[3])) +
                   ((r2[4] + r2[5]) + (r2[6] + r2[7]));
        out[bid] = ll + __logf(Sv);
    }
}

// V1: all-register A, waves_per_eu(4,4) to unlock the 512-reg/wave budget.
__global__ __attribute__((amdgpu_waves_per_eu(4, 4)))
__launch_bounds__(NTH) void hmm_v1(const float* __restrict__ emis,
                                   const uint4* __restrict__ wsA,
                                   const float* __restrict__ initd,
                                   float* __restrict__ out, int base) {
    hmm_body<32>(emis, wsA, initd, out, base + blockIdx.x);
}

// V2: proven 24-reg + 8-LDS split, fused phase2.
__global__ __launch_bounds__(NTH) void hmm_v2(const float* __restrict__ emis,
                                              const uint4* __restrict__ wsA,
                                              const float* __restrict__ initd,
                                              float* __restrict__ out, int base) {
    hmm_body<24>(emis, wsA, initd, out, base + blockIdx.x);
}

// ---- fallback (round-1 kernel) if ws is too small for packed A ----
__global__ __launch_bounds__(512) void hmm_forward_fb(
    const float* __restrict__ emis, const float* __restrict__ Aall,
    const float* __restrict__ initd, float* __restrict__ out)
{
    const int bid = blockIdx.x;
    const int m = bid / B;
    const int k = threadIdx.x;
    const int lane = k & 63, wid = k >> 6;
    const float* Am = Aall + (size_t)m * Q * Q;
    const float* E = emis + (size_t)bid * Q;
    const size_t stepStride = (size_t)M * B * Q;
    __shared__ float u_lds[Q];
    __shared__ float redf[8];
    float e = fmaxf(E[k], EPS);
    float r = fmaxf(initd[m * Q + k], EPS);
    float uval = e * r;
    float ll = 0.0f, invS = 1.0f;
    for (int t = 1; t <= L; ++t) {
        float ws = uval;
        #pragma unroll
        for (int off = 32; off >= 1; off >>= 1) ws += __shfl_xor(ws, off, 64);
        __syncthreads();
        u_lds[k] = uval;
        if (lane == 0) redf[wid] = ws;
        __syncthreads();
        float S = 0.0f;
        #pragma unroll
        for (int w = 0; w < 8; ++w) S += redf[w];
        ll += __logf(S);
        invS = 1.0f / S;
        if (t == L) break;
        float acc = 0.0f;
        #pragma unroll 8
        for (int q = 0; q < Q; ++q)
            acc = fmaf(u_lds[q], Am[q * Q + k], acc);
        float rr = fmaxf(acc * invS, EPS);
        float ee = fmaxf(E[(size_t)t * stepStride + k], EPS);
        uval = ee * rr;
    }
    if (k == 0) out[bid] = ll;
}

extern "C" void kernel_launch(void* const* d_in, const int* in_sizes, int n_in,
                              void* d_out, int out_size, void* d_ws, size_t ws_size,
                              hipStream_t stream) {
    const float* emis  = (const float*)d_in[0];  // (L, M, B, Q)
    const float* A     = (const float*)d_in[1];  // (M, Q, Q)
    const float* initd = (const float*)d_in[2];  // (M, Q)
    float* out = (float*)d_out;                  // (M, B)

    const size_t wsNeeded = (size_t)M * CHUNKS * NTH * 16;  // 1 MB
    if (ws_size < wsNeeded) {
        hipLaunchKernelGGL(hmm_forward_fb, dim3(M * B), dim3(512), 0, stream,
                           emis, A, initd, out);
        return;
    }

    const int smem_v1 = 1024 + 16384 + 64;                       // LCH=0
    const int smem_v2 = (CHUNKS - 24) * NTH * 16 + smem_v1;      // +128 KB
    (void)hipFuncSetAttribute((const void*)hmm_v1,
                              hipFuncAttributeMaxDynamicSharedMemorySize, smem_v1);
    (void)hipFuncSetAttribute((const void*)hmm_v2,
                              hipFuncAttributeMaxDynamicSharedMemorySize, smem_v2);

    uint4* wsA = (uint4*)d_ws;
    hipLaunchKernelGGL(pack_A, dim3(M * CHUNKS * NTH / 256), dim3(256), 0,
                       stream, A, wsA);
    hipLaunchKernelGGL(hmm_v1, dim3(64), dim3(NTH), smem_v1, stream,
                       emis, wsA, initd, out, 0);
    hipLaunchKernelGGL(hmm_v2, dim3(64), dim3(NTH), smem_v2, stream,
                       emis, wsA, initd, out, 64);
}

// Round 7
// 2568.187 us; speedup vs baseline: 1.1351x; 1.1351x over previous
//
#include <hip/hip_runtime.h>

// HMM scaled-forward V3: SGPR-broadcast of u (no LDS u-reads), redundant
// per-wave u computation, parity-buffered reductions.
// 64+64 wgs x 1024 threads = 8 q-groups x 128 col-threads; wave pair
// (2g,2g+1) both own u-slice g (64 states, one per lane).
// Per step: [barrier] read red2[pb] (S_prev) + red[pb] (matvec partials) ->
// u in-lane -> f16 -> 64 v_readlane -> 32 SGPR h2 words -> S-slice via
// dot2(word, 1) -> red2[cb]; dot phase: 128 dot2 (A from regs + LDS tail)
// -> red[cb]. u broadcast rides the VALU/SALU pipes (4x parallel per CU)
// instead of the single LDS pipe.
// A/B: v1 = VCH28/LCH4 + 1 barrier (parity red); v2 = VCH24/LCH8 + 2 barriers.

typedef _Float16 h2 __attribute__((ext_vector_type(2)));
typedef _Float16 h8 __attribute__((ext_vector_type(8)));

constexpr int Q = 512;
constexpr int L = 512;
constexpr int M = 2;
constexpr int B = 64;
constexpr int NTH = 1024;     // 8 q-groups x 128 col-threads
constexpr int CHUNKS = 32;    // h8 chunks per thread (128 h2 words)
constexpr float EPS = 1e-16f;

__device__ __forceinline__ float fdot2(h2 a, h2 b, float c) {
#if __has_builtin(__builtin_amdgcn_fdot2)
    return __builtin_amdgcn_fdot2(a, b, c, false);
#else
    return fmaf((float)a.x, (float)b.x, fmaf((float)a.y, (float)b.y, c));
#endif
}

// pack A (M,Q,Q) f32 -> per-thread chunk layout, f16 pairs over q.
// chunk c of thread t (qg=t>>7, ct=t&127): word j = (A[m][qg*64+2c][4ct+j],
// A[m][qg*64+2c+1][4ct+j]), stored at wsA[(m*32+c)*1024 + t].
__global__ __launch_bounds__(256) void pack_A(const float* __restrict__ A,
                                              uint4* __restrict__ wsA) {
    int idx = blockIdx.x * 256 + threadIdx.x;
    int t = idx & (NTH - 1);
    int c = (idx >> 10) & (CHUNKS - 1);
    int m = idx >> 15;
    int qg = t >> 7, ct = t & 127;
    int q0 = qg * 64 + 2 * c;
    const float* a0 = A + ((size_t)m * Q + q0) * Q + 4 * ct;
    float4 r0 = *(const float4*)a0;
    float4 r1 = *(const float4*)(a0 + Q);
    union { h2 w[4]; uint4 v; } cv;
    cv.w[0].x = (_Float16)r0.x; cv.w[0].y = (_Float16)r1.x;
    cv.w[1].x = (_Float16)r0.y; cv.w[1].y = (_Float16)r1.y;
    cv.w[2].x = (_Float16)r0.z; cv.w[2].y = (_Float16)r1.z;
    cv.w[3].x = (_Float16)r0.w; cv.w[3].y = (_Float16)r1.w;
    wsA[idx] = cv.v;
}

template<int VCH, bool ONEBAR>
__device__ __forceinline__ void hmm_body3(const float* __restrict__ emis,
                                          const uint4* __restrict__ wsA,
                                          const float* __restrict__ initd,
                                          float* __restrict__ out, int bid) {
    constexpr int LCH = CHUNKS - VCH;
    constexpr int NRED = ONEBAR ? 2 : 1;
    extern __shared__ char smem[];
    uint4* ldsA = (uint4*)smem;                                   // LCH*16 KB
    float* red  = (float*)(smem + (size_t)LCH * NTH * 16);        // NRED*16 KB
    float* red2 = (float*)(smem + (size_t)LCH * NTH * 16 +
                           (size_t)NRED * 8 * Q * 4);             // 2*8 f32

    const int t    = threadIdx.x;
    const int m    = bid >> 6;
    const int qg   = t >> 7;          // dot q-group AND u-slice index
    const int lane = t & 63;
    const int wv   = t >> 6;
    const int stq  = (qg << 6) | lane; // state this lane owns for u

    // ---- one-time A staging ----
    const uint4* wa = wsA + (size_t)m * CHUNKS * NTH + t;
    h8 areg[VCH];
    #pragma unroll
    for (int c = 0; c < VCH; ++c)
        areg[c] = *(const h8*)(wa + (size_t)c * NTH);
    #pragma unroll
    for (int s = 0; s < LCH; ++s)
        ldsA[s * NTH + t] = wa[(size_t)(VCH + s) * NTH];
    __syncthreads();   // ldsA visible before first dot phase

    const size_t stepStride = (size_t)M * B * Q;
    const float* Eq = emis + (size_t)bid * Q + stq;

    float ll = 0.0f;

    // u broadcast + S-slice + dot phase (shared by init and loop)
    auto phase_bcast_dot = [&](float uval, int cb) {
        _Float16 uh = (_Float16)uval;
        unsigned hu = (unsigned)__builtin_bit_cast(unsigned short, uh);
        const h2 one2 = {(_Float16)1.0f, (_Float16)1.0f};
        unsigned w[CHUNKS];
        float sacc = 0.0f;
        #pragma unroll
        for (int j = 0; j < CHUNKS; ++j) {      // 64 readlanes -> 32 SGPR words
            unsigned lo = (unsigned)__builtin_amdgcn_readlane((int)hu, 2 * j);
            unsigned hi = (unsigned)__builtin_amdgcn_readlane((int)hu, 2 * j + 1);
            w[j] = (lo & 0xffffu) | (hi << 16);
            sacc = fdot2(__builtin_bit_cast(h2, w[j]), one2, sacc);  // S-slice
        }
        if ((wv & 1) == 0 && lane == 0) red2[cb * 8 + qg] = sacc;
        float a0 = 0.f, a1 = 0.f, a2 = 0.f, a3 = 0.f;
        #pragma unroll
        for (int c = 0; c < CHUNKS; ++c) {
            h8 aw;
            if (c < VCH) aw = areg[c];
            else         aw = *(const h8*)(ldsA + (c - VCH) * NTH + t);
            h2 uw = __builtin_bit_cast(h2, w[c]);
            a0 = fdot2(aw.lo.lo, uw, a0);
            a1 = fdot2(aw.lo.hi, uw, a1);
            a2 = fdot2(aw.hi.lo, uw, a2);
            a3 = fdot2(aw.hi.hi, uw, a3);
        }
        float* rb = red + (ONEBAR ? (size_t)cb * 8 * Q : (size_t)0);
        float4 rv; rv.x = a0; rv.y = a1; rv.z = a2; rv.w = a3;
        *(float4*)(rb + qg * Q + 4 * (t & 127)) = rv;
    };

    // ---- step 0: u0 from E0 and init_dist ----
    float u0 = fmaxf(Eq[0], EPS) * fmaxf(initd[m * Q + stq], EPS);
    float ep = Eq[stepStride];            // prefetch E_1
    phase_bcast_dot(u0, 0);

    for (int step = 1; step < L; ++step) {
        const int pb = (step - 1) & 1;
        const int cb = step & 1;
        __syncthreads();                   // red[pb]/red2[pb] now visible
        float4 rA = *(const float4*)&red2[pb * 8];
        float4 rB = *(const float4*)&red2[pb * 8 + 4];
        float Sv  = ((rA.x + rA.y) + (rA.z + rA.w)) +
                    ((rB.x + rB.y) + (rB.z + rB.w));
        float inv = 1.0f / Sv;
        ll += __logf(Sv);
        const float* rb = red + (ONEBAR ? (size_t)pb * 8 * Q : (size_t)0);
        float racc = 0.f;
        #pragma unroll
        for (int g = 0; g < 8; ++g) racc += rb[g * Q + stq];
        float uv = fmaxf(ep, EPS) * fmaxf(racc * inv, EPS);
        int ns = (step + 1 < L) ? step + 1 : L - 1;
        ep = Eq[(size_t)ns * stepStride];  // prefetch next E, hidden by dots
        if constexpr (!ONEBAR) __syncthreads();   // reads done before red rewrite
        phase_bcast_dot(uv, cb);
    }

    __syncthreads();
    {
        const int lb = (L - 1) & 1;
        float4 rA = *(const float4*)&red2[lb * 8];
        float4 rB = *(const float4*)&red2[lb * 8 + 4];
        float Sv  = ((rA.x + rA.y) + (rA.z + rA.w)) +
                    ((rB.x + rB.y) + (rB.z + rB.w));
        if (t == 0) out[bid] = ll + __logf(Sv);
    }
}

// v1: VCH=28/LCH=4, parity red, ONE barrier/step. LDS = 98368 B.
__global__ __launch_bounds__(NTH) void hmm_v1(const float* __restrict__ emis,
                                              const uint4* __restrict__ wsA,
                                              const float* __restrict__ initd,
                                              float* __restrict__ out, int base) {
    hmm_body3<28, true>(emis, wsA, initd, out, base + blockIdx.x);
}

// v2: VCH=24/LCH=8 (proven no-spill), single red, TWO barriers/step. 147520 B.
__global__ __launch_bounds__(NTH) void hmm_v2(const float* __restrict__ emis,
                                              const uint4* __restrict__ wsA,
                                              const float* __restrict__ initd,
                                              float* __restrict__ out, int base) {
    hmm_body3<24, false>(emis, wsA, initd, out, base + blockIdx.x);
}

// ---- fallback (round-1 kernel) if ws is too small for packed A ----
__global__ __launch_bounds__(512) void hmm_forward_fb(
    const float* __restrict__ emis, const float* __restrict__ Aall,
    const float* __restrict__ initd, float* __restrict__ out)
{
    const int bid = blockIdx.x;
    const int m = bid / B;
    const int k = threadIdx.x;
    const int lane = k & 63, wid = k >> 6;
    const float* Am = Aall + (size_t)m * Q * Q;
    const float* E = emis + (size_t)bid * Q;
    const size_t stepStride = (size_t)M * B * Q;
    __shared__ float u_lds[Q];
    __shared__ float redf[8];
    float e = fmaxf(E[k], EPS);
    float r = fmaxf(initd[m * Q + k], EPS);
    float uval = e * r;
    float ll = 0.0f, invS = 1.0f;
    for (int t = 1; t <= L; ++t) {
        float ws = uval;
        #pragma unroll
        for (int off = 32; off >= 1; off >>= 1) ws += __shfl_xor(ws, off, 64);
        __syncthreads();
        u_lds[k] = uval;
        if (lane == 0) redf[wid] = ws;
        __syncthreads();
        float S = 0.0f;
        #pragma unroll
        for (int w = 0; w < 8; ++w) S += redf[w];
        ll += __logf(S);
        invS = 1.0f / S;
        if (t == L) break;
        float acc = 0.0f;
        #pragma unroll 8
        for (int q = 0; q < Q; ++q)
            acc = fmaf(u_lds[q], Am[q * Q + k], acc);
        float rr = fmaxf(acc * invS, EPS);
        float ee = fmaxf(E[(size_t)t * stepStride + k], EPS);
        uval = ee * rr;
    }
    if (k == 0) out[bid] = ll;
}

extern "C" void kernel_launch(void* const* d_in, const int* in_sizes, int n_in,
                              void* d_out, int out_size, void* d_ws, size_t ws_size,
                              hipStream_t stream) {
    const float* emis  = (const float*)d_in[0];  // (L, M, B, Q)
    const float* A     = (const float*)d_in[1];  // (M, Q, Q)
    const float* initd = (const float*)d_in[2];  // (M, Q)
    float* out = (float*)d_out;                  // (M, B)

    const size_t wsNeeded = (size_t)M * CHUNKS * NTH * 16;  // 1 MB
    if (ws_size < wsNeeded) {
        hipLaunchKernelGGL(hmm_forward_fb, dim3(M * B), dim3(512), 0, stream,
                           emis, A, initd, out);
        return;
    }

    const int smem_v1 = 4 * NTH * 16 + 2 * 8 * Q * 4 + 64;  // 98368
    const int smem_v2 = 8 * NTH * 16 + 1 * 8 * Q * 4 + 64;  // 147520
    (void)hipFuncSetAttribute((const void*)hmm_v1,
                              hipFuncAttributeMaxDynamicSharedMemorySize, smem_v1);
    (void)hipFuncSetAttribute((const void*)hmm_v2,
                              hipFuncAttributeMaxDynamicSharedMemorySize, smem_v2);

    uint4* wsA = (uint4*)d_ws;
    hipLaunchKernelGGL(pack_A, dim3(M * CHUNKS * NTH / 256), dim3(256), 0,
                       stream, A, wsA);
    hipLaunchKernelGGL(hmm_v1, dim3(64), dim3(NTH), smem_v1, stream,
                       emis, wsA, initd, out, 0);
    hipLaunchKernelGGL(hmm_v2, dim3(64), dim3(NTH), smem_v2, stream,
                       emis, wsA, initd, out, 64);
}

// Round 9
// 1556.638 us; speedup vs baseline: 1.8727x; 1.6498x over previous
//
#include <hip/hip_runtime.h>

// HMM scaled-forward — in-dispatch A/B (round-8 retry; fixed ldsU/red2 overlap:
// ldsU parity buffer is 2048 B, red2 now at +2048 — was the inf bug).
// Blocks 0..63  (m=0): NEW column-owning path — thread owns 1 column (half each
//   of a lane pair), halves combined via shfl_xor(1); no red matrix, ONE
//   barrier/step (parity ldsU+red2).
// Blocks 64..127 (m=1): PROVEN round-6-v2 path (VCH24/LCH8, fused wide phase2,
//   2 barriers/step, ~780 us per 64 seqs).
// Both run concurrently on different CUs in one dispatch.

typedef _Float16 h2 __attribute__((ext_vector_type(2)));
typedef _Float16 h8 __attribute__((ext_vector_type(8)));

constexpr int Q = 512;
constexpr int L = 512;
constexpr int M = 2;
constexpr int B = 64;
constexpr int NTH = 1024;
constexpr int CHUNKS = 32;    // h8 chunks per thread (128 h2 words)
constexpr int VCH = 24;       // proven no-spill register chunk count
constexpr int LCH = CHUNKS - VCH;
constexpr float EPS = 1e-16f;

// old-path smem: ldsA 128K + ldsU 1K + red 16K + red2 64B = 148544
// new-path smem: ldsA 128K + ldsU 2K + red2 128B       = 133248  (< old)
constexpr int SMEM_BYTES = LCH * NTH * 16 + 1024 + 8 * Q * 4 + 64;

__device__ __forceinline__ float fdot2(h2 a, h2 b, float c) {
#if __has_builtin(__builtin_amdgcn_fdot2)
    return __builtin_amdgcn_fdot2(a, b, c, false);
#else
    return fmaf((float)a.x, (float)b.x, fmaf((float)a.y, (float)b.y, c));
#endif
}

// ---- pack for OLD path: thread t (qg=t>>7, ct=t&127), chunk c:
// word j = (A[m][qg*64+2c][4ct+j], A[m][qg*64+2c+1][4ct+j])
__global__ __launch_bounds__(256) void pack_A(const float* __restrict__ A,
                                              uint4* __restrict__ wsA) {
    int idx = blockIdx.x * 256 + threadIdx.x;
    int t = idx & (NTH - 1);
    int c = (idx >> 10) & (CHUNKS - 1);
    int m = idx >> 15;
    int qg = t >> 7, ct = t & 127;
    int q0 = qg * 64 + 2 * c;
    const float* a0 = A + ((size_t)m * Q + q0) * Q + 4 * ct;
    float4 r0 = *(const float4*)a0;
    float4 r1 = *(const float4*)(a0 + Q);
    union { h2 w[4]; uint4 v; } cv;
    cv.w[0].x = (_Float16)r0.x; cv.w[0].y = (_Float16)r1.x;
    cv.w[1].x = (_Float16)r0.y; cv.w[1].y = (_Float16)r1.y;
    cv.w[2].x = (_Float16)r0.z; cv.w[2].y = (_Float16)r1.z;
    cv.w[3].x = (_Float16)r0.w; cv.w[3].y = (_Float16)r1.w;
    wsA[idx] = cv.v;
}

// ---- pack for NEW path: thread t (col=t>>1, half=t&1), chunk c:
// word j = (A[m][2p][col], A[m][2p+1][col]), p = half*128 + 4c + j
__global__ __launch_bounds__(256) void pack_A2(const float* __restrict__ A,
                                               uint4* __restrict__ wsB) {
    int idx = blockIdx.x * 256 + threadIdx.x;
    int t = idx & (NTH - 1);
    int c = (idx >> 10) & (CHUNKS - 1);
    int m = idx >> 15;
    int col = t >> 1, half = t & 1;
    int p0 = half * 128 + 4 * c;
    const float* Am = A + (size_t)m * Q * Q;
    union { h2 w[4]; uint4 v; } cv;
    #pragma unroll
    for (int j = 0; j < 4; ++j) {
        int q0 = 2 * (p0 + j);
        cv.w[j].x = (_Float16)Am[(size_t)q0 * Q + col];
        cv.w[j].y = (_Float16)Am[(size_t)(q0 + 1) * Q + col];
    }
    wsB[idx] = cv.v;
}

// ================= OLD path (round-6-v2 verbatim) =================
__device__ __forceinline__ void old_body(const float* __restrict__ emis,
                                         const uint4* __restrict__ wsA,
                                         const float* __restrict__ initd,
                                         float* __restrict__ out,
                                         int bid, char* smem) {
    uint4* ldsA = (uint4*)smem;
    h2*    ldsU = (h2*)(smem + (size_t)LCH * NTH * 16);
    float* red  = (float*)(smem + (size_t)LCH * NTH * 16 + 1024);
    float (*red2)[8] = (float (*)[8])(smem + (size_t)LCH * NTH * 16 + 1024 + 8 * Q * 4);

    const int t  = threadIdx.x;
    const int m  = bid >> 6;
    const int qg = t >> 7;

    const uint4* wa = wsA + (size_t)m * CHUNKS * NTH + t;
    h8 areg[VCH];
    #pragma unroll
    for (int c = 0; c < VCH; ++c)
        areg[c] = *(const h8*)(wa + (size_t)c * NTH);
    #pragma unroll
    for (int s = 0; s < LCH; ++s)
        ldsA[s * NTH + t] = wa[(size_t)(VCH + s) * NTH];

    const float* E = emis + (size_t)bid * Q;
    const size_t stepStride = (size_t)M * B * Q;

    float ll = 0.0f;

    if (t < Q) {
        float u = fmaxf(E[t], EPS) * fmaxf(initd[m * Q + t], EPS);
        float uy = __shfl_xor(u, 1, 64);
        if (!(t & 1)) { h2 w; w.x = (_Float16)u; w.y = (_Float16)uy; ldsU[t >> 1] = w; }
        float s = u;
        #pragma unroll
        for (int off = 32; off >= 1; off >>= 1) s += __shfl_xor(s, off, 64);
        if ((t & 63) == 0) red2[0][t >> 6] = s;
    }
    __syncthreads();

    const float* Ep = E + stepStride + t;

    for (int step = 1; step < L; ++step) {
        const int pp = (step + 1) & 1;
        const int cp = step & 1;

        float ep = 0.0f;
        if (t < Q) ep = *Ep;
        Ep += stepStride;

        float a0 = 0.f, a1 = 0.f, a2 = 0.f, a3 = 0.f;
        const h8* uq8 = (const h8*)(ldsU + qg * 32);
        #pragma unroll
        for (int i = 0; i < 8; ++i) {
            h8 uw = uq8[i];
            h2 ups[4] = {uw.lo.lo, uw.lo.hi, uw.hi.lo, uw.hi.hi};
            #pragma unroll
            for (int p = 0; p < 4; ++p) {
                const int c = 4 * i + p;
                h8 aw;
                if (c < VCH) aw = areg[c];
                else         aw = *(const h8*)(ldsA + (c - VCH) * NTH + t);
                a0 = fdot2(aw.lo.lo, ups[p], a0);
                a1 = fdot2(aw.lo.hi, ups[p], a1);
                a2 = fdot2(aw.hi.lo, ups[p], a2);
                a3 = fdot2(aw.hi.hi, ups[p], a3);
            }
        }
        float4 rv; rv.x = a0; rv.y = a1; rv.z = a2; rv.w = a3;
        *(float4*)(&red[qg * Q + 4 * (t & 127)]) = rv;
        __syncthreads();

        if (t < Q) {
            float4 rA = *(const float4*)&red2[pp][0];
            float4 rB = *(const float4*)&red2[pp][4];
            float acc = 0.f;
            #pragma unroll
            for (int g = 0; g < 8; ++g) acc += red[g * Q + t];
            float Sv = ((rA.x + rA.y) + (rA.z + rA.w)) +
                       ((rB.x + rB.y) + (rB.z + rB.w));
            float inv = 1.0f / Sv;
            ll += __logf(Sv);
            float r = fmaxf(acc * inv, EPS);
            float e = fmaxf(ep, EPS);
            float u = e * r;
            float uy = __shfl_xor(u, 1, 64);
            if (!(t & 1)) { h2 w; w.x = (_Float16)u; w.y = (_Float16)uy; ldsU[t >> 1] = w; }
            float s = u;
            #pragma unroll
            for (int off = 32; off >= 1; off >>= 1) s += __shfl_xor(s, off, 64);
            if ((t & 63) == 0) red2[cp][t >> 6] = s;
        }
        __syncthreads();
    }

    if (t == 0) {
        const float* r2 = red2[(L - 1) & 1];
        float Sv = ((r2[0] + r2[1]) + (r2[2] + r2[3])) +
                   ((r2[4] + r2[5]) + (r2[6] + r2[7]));
        out[bid] = ll + __logf(Sv);
    }
}

// ================= NEW path: column-owning, one barrier/step =================
__device__ __forceinline__ void new_body(const float* __restrict__ emis,
                                         const uint4* __restrict__ wsB,
                                         const float* __restrict__ initd,
                                         float* __restrict__ out,
                                         int bid, char* smem) {
    uint4* ldsA = (uint4*)smem;                                    // 128 KB
    h2*    ldsU = (h2*)(smem + (size_t)LCH * NTH * 16);            // [2][256] = 2048 B
    float* red2 = (float*)(smem + (size_t)LCH * NTH * 16 + 2048);  // [2][16] (FIXED)

    const int t    = threadIdx.x;
    const int m    = bid >> 6;
    const int col  = t >> 1;
    const int half = t & 1;
    const int lane = t & 63;
    const int wv   = t >> 6;

    const uint4* wa = wsB + (size_t)m * CHUNKS * NTH + t;
    h8 areg[VCH];
    #pragma unroll
    for (int c = 0; c < VCH; ++c)
        areg[c] = *(const h8*)(wa + (size_t)c * NTH);
    #pragma unroll
    for (int s = 0; s < LCH; ++s)
        ldsA[s * NTH + t] = wa[(size_t)(VCH + s) * NTH];

    const size_t stepStride = (size_t)M * B * Q;
    const float* Eq = emis + (size_t)bid * Q + col;

    // publish u (all lanes hold u of their col): pack pairs in-wave, wave-sum S
    auto publish = [&](float u, int b) {
        float un = __shfl_down(u, 2, 64);           // u of col+1
        if ((lane & 3) == 0) {
            h2 w; w.x = (_Float16)u; w.y = (_Float16)un;
            ldsU[b * 256 + wv * 16 + (lane >> 2)] = w;   // word i = states (2i,2i+1)
        }
        float s = u;                                 // stride-2 reduce: even/odd
        #pragma unroll                               // class each sums its wave's
        for (int off = 2; off <= 32; off <<= 1)      // 32 distinct cols once
            s += __shfl_xor(s, off, 64);
        if (lane == 0) red2[b * 16 + wv] = s;
    };

    float ep = Eq[0];
    float u0 = fmaxf(ep, EPS) * fmaxf(initd[m * Q + col], EPS);
    publish(u0, 0);
    ep = Eq[stepStride];                             // prefetch E_1
    float ll = 0.0f;

    for (int step = 1; step < L; ++step) {
        const int pb = (step - 1) & 1;
        const int cb = step & 1;
        __syncthreads();   // red2[pb]/ldsU[pb] visible; prior reads of [cb] done

        const float4* r4 = (const float4*)(red2 + pb * 16);
        float4 s0 = r4[0], s1 = r4[1], s2 = r4[2], s3 = r4[3];
        float Sv = (((s0.x + s0.y) + (s0.z + s0.w)) +
                    ((s1.x + s1.y) + (s1.z + s1.w))) +
                   (((s2.x + s2.y) + (s2.z + s2.w)) +
                    ((s3.x + s3.y) + (s3.z + s3.w)));
        float inv = 1.0f / Sv;
        ll += __logf(Sv);

        // dots: 32 chunks x 4 q-pairs for ONE column; u via LDS broadcast
        const h8* ub = (const h8*)(ldsU + pb * 256 + half * 128);
        float acc0 = 0.f, acc1 = 0.f;
        #pragma unroll
        for (int i = 0; i < CHUNKS; ++i) {
            h8 uw = ub[i];
            h8 aw;
            if (i < VCH) aw = areg[i];
            else         aw = *(const h8*)(ldsA + (i - VCH) * NTH + t);
            if (i & 1) {
                acc1 = fdot2(aw.lo.lo, uw.lo.lo, acc1);
                acc1 = fdot2(aw.lo.hi, uw.lo.hi, acc1);
                acc1 = fdot2(aw.hi.lo, uw.hi.lo, acc1);
                acc1 = fdot2(aw.hi.hi, uw.hi.hi, acc1);
            } else {
                acc0 = fdot2(aw.lo.lo, uw.lo.lo, acc0);
                acc0 = fdot2(aw.lo.hi, uw.lo.hi, acc0);
                acc0 = fdot2(aw.hi.lo, uw.hi.lo, acc0);
                acc0 = fdot2(aw.hi.hi, uw.hi.hi, acc0);
            }
        }
        float acc = acc0 + acc1;
        float R = acc + __shfl_xor(acc, 1, 64);      // combine halves in-wave
        float uv = fmaxf(ep, EPS) * fmaxf(R * inv, EPS);
        int ns = (step + 1 < L) ? step + 1 : L - 1;
        ep = Eq[(size_t)ns * stepStride];            // prefetch next E
        publish(uv, cb);
    }

    __syncthreads();
    if (t == 0) {
        const float* r2 = red2 + ((L - 1) & 1) * 16;
        float Sv = 0.f;
        #pragma unroll
        for (int w = 0; w < 16; ++w) Sv += r2[w];
        out[bid] = ll + __logf(Sv);
    }
}

// combined A/B dispatch: blocks <64 new, >=64 old (concurrent on distinct CUs)
__global__ __launch_bounds__(NTH) void hmm_ab(const float* __restrict__ emis,
                                              const uint4* __restrict__ wsA,
                                              const uint4* __restrict__ wsB,
                                              const float* __restrict__ initd,
                                              float* __restrict__ out) {
    extern __shared__ char smem[];
    int bid = blockIdx.x;
    if (bid < 64) new_body(emis, wsB, initd, out, bid, smem);
    else          old_body(emis, wsA, initd, out, bid, smem);
}

// all-old kernel for smaller ws
__global__ __launch_bounds__(NTH) void hmm_old(const float* __restrict__ emis,
                                               const uint4* __restrict__ wsA,
                                               const float* __restrict__ initd,
                                               float* __restrict__ out) {
    extern __shared__ char smem[];
    old_body(emis, wsA, initd, out, blockIdx.x, smem);
}

// ---- fallback (round-1 kernel) if ws too small for packed A ----
__global__ __launch_bounds__(512) void hmm_forward_fb(
    const float* __restrict__ emis, const float* __restrict__ Aall,
    const float* __restrict__ initd, float* __restrict__ out)
{
    const int bid = blockIdx.x;
    const int m = bid / B;
    const int k = threadIdx.x;
    const int lane = k & 63, wid = k >> 6;
    const float* Am = Aall + (size_t)m * Q * Q;
    const float* E = emis + (size_t)bid * Q;
    const size_t stepStride = (size_t)M * B * Q;
    __shared__ float u_lds[Q];
    __shared__ float redf[8];
    float e = fmaxf(E[k], EPS);
    float r = fmaxf(initd[m * Q + k], EPS);
    float uval = e * r;
    float ll = 0.0f, invS = 1.0f;
    for (int t = 1; t <= L; ++t) {
        float ws = uval;
        #pragma unroll
        for (int off = 32; off >= 1; off >>= 1) ws += __shfl_xor(ws, off, 64);
        __syncthreads();
        u_lds[k] = uval;
        if (lane == 0) redf[wid] = ws;
        __syncthreads();
        float S = 0.0f;
        #pragma unroll
        for (int w = 0; w < 8; ++w) S += redf[w];
        ll += __logf(S);
        invS = 1.0f / S;
        if (t == L) break;
        float acc = 0.0f;
        #pragma unroll 8
        for (int q = 0; q < Q; ++q)
            acc = fmaf(u_lds[q], Am[q * Q + k], acc);
        float rr = fmaxf(acc * invS, EPS);
        float ee = fmaxf(E[(size_t)t * stepStride + k], EPS);
        uval = ee * rr;
    }
    if (k == 0) out[bid] = ll;
}

extern "C" void kernel_launch(void* const* d_in, const int* in_sizes, int n_in,
                              void* d_out, int out_size, void* d_ws, size_t ws_size,
                              hipStream_t stream) {
    const float* emis  = (const float*)d_in[0];  // (L, M, B, Q)
    const float* A     = (const float*)d_in[1];  // (M, Q, Q)
    const float* initd = (const float*)d_in[2];  // (M, Q)
    float* out = (float*)d_out;                  // (M, B)

    const size_t packElems = (size_t)M * CHUNKS * NTH;   // uint4 count (1 MB)
    uint4* wsA = (uint4*)d_ws;
    uint4* wsB = wsA + packElems;

    (void)hipFuncSetAttribute((const void*)hmm_ab,
                              hipFuncAttributeMaxDynamicSharedMemorySize, SMEM_BYTES);
    (void)hipFuncSetAttribute((const void*)hmm_old,
                              hipFuncAttributeMaxDynamicSharedMemorySize, SMEM_BYTES);

    if (ws_size >= 2 * packElems * sizeof(uint4)) {
        hipLaunchKernelGGL(pack_A,  dim3(M * CHUNKS * NTH / 256), dim3(256), 0,
                           stream, A, wsA);
        hipLaunchKernelGGL(pack_A2, dim3(M * CHUNKS * NTH / 256), dim3(256), 0,
                           stream, A, wsB);
        hipLaunchKernelGGL(hmm_ab, dim3(M * B), dim3(NTH), SMEM_BYTES, stream,
                           emis, wsA, wsB, initd, out);
    } else if (ws_size >= packElems * sizeof(uint4)) {
        hipLaunchKernelGGL(pack_A, dim3(M * CHUNKS * NTH / 256), dim3(256), 0,
                           stream, A, wsA);
        hipLaunchKernelGGL(hmm_old, dim3(M * B), dim3(NTH), SMEM_BYTES, stream,
                           emis, wsA, initd, out);
    } else {
        hipLaunchKernelGGL(hmm_forward_fb, dim3(M * B), dim3(512), 0, stream,
                           emis, A, initd, out);
    }
}

// Round 10
// 1326.727 us; speedup vs baseline: 2.1972x; 1.1733x over previous
//
#include <hip/hip_runtime.h>

// HMM scaled-forward — round-6-v2 structure (proven ~780us/64seq), single
// lever changed: VCH 24 -> 28 (LCH 8 -> 4). Halves per-step LDS A-traffic
// (1536 -> 768 cyc/CU/step). Spill-cliff theory: AGPR cap ~128/wave;
// 112 A-words fits (24=96 OK, 32=128+temps spilled). Diagnostic: WRITE_SIZE.
// 128 wgs x 1024 threads = 8 q-groups x 128 col-threads, one wg per (m,b).
// Per step: phase1 128 dot2/thread (A regs + 4 LDS chunks) -> red (b128);
// barrier; phase2 (512 thr) S(prev) from parity red2 + 8-way reduce + renorm
// + new u (f16) -> ldsU + wave-sum -> red2[parity]; barrier.

typedef _Float16 h2 __attribute__((ext_vector_type(2)));
typedef _Float16 h8 __attribute__((ext_vector_type(8)));

constexpr int Q = 512;
constexpr int L = 512;
constexpr int M = 2;
constexpr int B = 64;
constexpr int NTH = 1024;     // 8 q-groups x 128 col-threads
constexpr int CHUNKS = 32;    // h8 chunks per thread (128 h2 words)
constexpr int VCH = 28;       // chunks in registers (112 words; theory: <=128 AGPR fits)
constexpr int LCH = CHUNKS - VCH;   // 4 chunks via LDS
constexpr float EPS = 1e-16f;

// smem: ldsA 64K + ldsU 1K + red 16K + red2 64B = 83008 B
constexpr int SMEM_BYTES = LCH * NTH * 16 + 1024 + 8 * Q * 4 + 64;

__device__ __forceinline__ float fdot2(h2 a, h2 b, float c) {
#if __has_builtin(__builtin_amdgcn_fdot2)
    return __builtin_amdgcn_fdot2(a, b, c, false);
#else
    return fmaf((float)a.x, (float)b.x, fmaf((float)a.y, (float)b.y, c));
#endif
}

// pack A (M,Q,Q) f32 -> per-thread chunk layout, f16 pairs over q.
// chunk c of thread t (qg=t>>7, ct=t&127): word j = (A[m][qg*64+2c][4ct+j],
// A[m][qg*64+2c+1][4ct+j]), stored at wsA[(m*32+c)*1024 + t].
__global__ __launch_bounds__(256) void pack_A(const float* __restrict__ A,
                                              uint4* __restrict__ wsA) {
    int idx = blockIdx.x * 256 + threadIdx.x;
    int t = idx & (NTH - 1);
    int c = (idx >> 10) & (CHUNKS - 1);
    int m = idx >> 15;
    int qg = t >> 7, ct = t & 127;
    int q0 = qg * 64 + 2 * c;
    const float* a0 = A + ((size_t)m * Q + q0) * Q + 4 * ct;
    float4 r0 = *(const float4*)a0;
    float4 r1 = *(const float4*)(a0 + Q);
    union { h2 w[4]; uint4 v; } cv;
    cv.w[0].x = (_Float16)r0.x; cv.w[0].y = (_Float16)r1.x;
    cv.w[1].x = (_Float16)r0.y; cv.w[1].y = (_Float16)r1.y;
    cv.w[2].x = (_Float16)r0.z; cv.w[2].y = (_Float16)r1.z;
    cv.w[3].x = (_Float16)r0.w; cv.w[3].y = (_Float16)r1.w;
    wsA[idx] = cv.v;
}

__global__ __launch_bounds__(NTH) void hmm_fwd(
    const float* __restrict__ emis,   // (L, M, B, Q)
    const uint4* __restrict__ wsA,    // packed A
    const float* __restrict__ initd,  // (M, Q)
    float* __restrict__ out)          // (M, B)
{
    extern __shared__ char smem[];
    uint4* ldsA = (uint4*)smem;
    h2*    ldsU = (h2*)(smem + (size_t)LCH * NTH * 16);
    float* red  = (float*)(smem + (size_t)LCH * NTH * 16 + 1024);
    float (*red2)[8] = (float (*)[8])(smem + (size_t)LCH * NTH * 16 + 1024 + 8 * Q * 4);

    const int t   = threadIdx.x;
    const int bid = blockIdx.x;       // m*B + b
    const int m   = bid >> 6;
    const int qg  = t >> 7;

    // ---- one-time A staging: 28 chunks -> regs, 4 -> LDS ----
    const uint4* wa = wsA + (size_t)m * CHUNKS * NTH + t;
    h8 areg[VCH];
    #pragma unroll
    for (int c = 0; c < VCH; ++c)
        areg[c] = *(const h8*)(wa + (size_t)c * NTH);
    #pragma unroll
    for (int s = 0; s < LCH; ++s)
        ldsA[s * NTH + t] = wa[(size_t)(VCH + s) * NTH];

    const float* E = emis + (size_t)bid * Q;
    const size_t stepStride = (size_t)M * B * Q;

    float ll = 0.0f;

    // ---- init: u0 = max(E0,eps) * max(init,eps), one state per thread ----
    if (t < Q) {
        float u = fmaxf(E[t], EPS) * fmaxf(initd[m * Q + t], EPS);
        float uy = __shfl_xor(u, 1, 64);
        if (!(t & 1)) { h2 w; w.x = (_Float16)u; w.y = (_Float16)uy; ldsU[t >> 1] = w; }
        float s = u;
        #pragma unroll
        for (int off = 32; off >= 1; off >>= 1) s += __shfl_xor(s, off, 64);
        if ((t & 63) == 0) red2[0][t >> 6] = s;
    }
    __syncthreads();   // covers ldsA/ldsU/red2 staging

    const float* Ep = E + stepStride + t;

    for (int step = 1; step < L; ++step) {
        const int pp = (step + 1) & 1;      // red2 buffer holding S(step-1)
        const int cp = step & 1;

        float ep = 0.0f;
        if (t < Q) ep = *Ep;                // prefetch, consumed in phase2
        Ep += stepStride;

        // ---- phase1: 4 output cols x 64 q of my q-group ----
        float a0 = 0.f, a1 = 0.f, a2 = 0.f, a3 = 0.f;
        const h8* uq8 = (const h8*)(ldsU + qg * 32);   // wave-uniform broadcast
        #pragma unroll
        for (int i = 0; i < 8; ++i) {
            h8 uw = uq8[i];
            h2 ups[4] = {uw.lo.lo, uw.lo.hi, uw.hi.lo, uw.hi.hi};
            #pragma unroll
            for (int p = 0; p < 4; ++p) {
                const int c = 4 * i + p;
                h8 aw;
                if (c < VCH) aw = areg[c];
                else         aw = *(const h8*)(ldsA + (c - VCH) * NTH + t);
                a0 = fdot2(aw.lo.lo, ups[p], a0);
                a1 = fdot2(aw.lo.hi, ups[p], a1);
                a2 = fdot2(aw.hi.lo, ups[p], a2);
                a3 = fdot2(aw.hi.hi, ups[p], a3);
            }
        }
        float4 rv; rv.x = a0; rv.y = a1; rv.z = a2; rv.w = a3;
        *(float4*)(&red[qg * Q + 4 * (t & 127)]) = rv;
        __syncthreads();

        // ---- phase2 (t<512): S(prev), 8-way reduce, renorm, new u ----
        if (t < Q) {
            float4 rA = *(const float4*)&red2[pp][0];
            float4 rB = *(const float4*)&red2[pp][4];
            float acc = 0.f;
            #pragma unroll
            for (int g = 0; g < 8; ++g) acc += red[g * Q + t];
            float Sv = ((rA.x + rA.y) + (rA.z + rA.w)) +
                       ((rB.x + rB.y) + (rB.z + rB.w));
            float inv = 1.0f / Sv;
            ll += __logf(Sv);
            float r = fmaxf(acc * inv, EPS);
            float e = fmaxf(ep, EPS);
            float u = e * r;
            float uy = __shfl_xor(u, 1, 64);
            if (!(t & 1)) { h2 w; w.x = (_Float16)u; w.y = (_Float16)uy; ldsU[t >> 1] = w; }
            float s = u;
            #pragma unroll
            for (int off = 32; off >= 1; off >>= 1) s += __shfl_xor(s, off, 64);
            if ((t & 63) == 0) red2[cp][t >> 6] = s;
        }
        __syncthreads();
    }

    if (t == 0) {
        const float* r2 = red2[(L - 1) & 1];
        float Sv = ((r2[0] + r2[1]) + (r2[2] + r2[3])) +
                   ((r2[4] + r2[5]) + (r2[6] + r2[7]));
        out[bid] = ll + __logf(Sv);
    }
}

// ---- fallback (round-1 kernel) if ws too small for packed A ----
__global__ __launch_bounds__(512) void hmm_forward_fb(
    const float* __restrict__ emis, const float* __restrict__ Aall,
    const float* __restrict__ initd, float* __restrict__ out)
{
    const int bid = blockIdx.x;
    const int m = bid / B;
    const int k = threadIdx.x;
    const int lane = k & 63, wid = k >> 6;
    const float* Am = Aall + (size_t)m * Q * Q;
    const float* E = emis + (size_t)bid * Q;
    const size_t stepStride = (size_t)M * B * Q;
    __shared__ float u_lds[Q];
    __shared__ float redf[8];
    float e = fmaxf(E[k], EPS);
    float r = fmaxf(initd[m * Q + k], EPS);
    float uval = e * r;
    float ll = 0.0f, invS = 1.0f;
    for (int t = 1; t <= L; ++t) {
        float ws = uval;
        #pragma unroll
        for (int off = 32; off >= 1; off >>= 1) ws += __shfl_xor(ws, off, 64);
        __syncthreads();
        u_lds[k] = uval;
        if (lane == 0) redf[wid] = ws;
        __syncthreads();
        float S = 0.0f;
        #pragma unroll
        for (int w = 0; w < 8; ++w) S += redf[w];
        ll += __logf(S);
        invS = 1.0f / S;
        if (t == L) break;
        float acc = 0.0f;
        #pragma unroll 8
        for (int q = 0; q < Q; ++q)
            acc = fmaf(u_lds[q], Am[q * Q + k], acc);
        float rr = fmaxf(acc * invS, EPS);
        float ee = fmaxf(E[(size_t)t * stepStride + k], EPS);
        uval = ee * rr;
    }
    if (k == 0) out[bid] = ll;
}

extern "C" void kernel_launch(void* const* d_in, const int* in_sizes, int n_in,
                              void* d_out, int out_size, void* d_ws, size_t ws_size,
                              hipStream_t stream) {
    const float* emis  = (const float*)d_in[0];  // (L, M, B, Q)
    const float* A     = (const float*)d_in[1];  // (M, Q, Q)
    const float* initd = (const float*)d_in[2];  // (M, Q)
    float* out = (float*)d_out;                  // (M, B)

    const size_t wsNeeded = (size_t)M * CHUNKS * NTH * 16;  // 1 MB
    if (ws_size < wsNeeded) {
        hipLaunchKernelGGL(hmm_forward_fb, dim3(M * B), dim3(512), 0, stream,
                           emis, A, initd, out);
        return;
    }

    (void)hipFuncSetAttribute((const void*)hmm_fwd,
                              hipFuncAttributeMaxDynamicSharedMemorySize,
                              SMEM_BYTES);

    uint4* wsA = (uint4*)d_ws;
    hipLaunchKernelGGL(pack_A, dim3(M * CHUNKS * NTH / 256), dim3(256), 0,
                       stream, A, wsA);
    hipLaunchKernelGGL(hmm_fwd, dim3(M * B), dim3(NTH), SMEM_BYTES, stream,
                       emis, wsA, initd, out);
}